// Round 1
// 690.556 us; speedup vs baseline: 1.0324x; 1.0324x over previous
//
#include <hip/hip_runtime.h>
#include <cstdint>

#define D_DIM 1024
#define V_DIM 32000
#define S_DIM 512
#define M_TOK 77
#define ROWS 2464
#define ROWS_PAD 2560

// ---- gemm2 (256^2 8-phase) geometry ----
#define G2_BM 256
#define G2_BN 256
#define G2_BK 64
#define G2_MT (ROWS_PAD / G2_BM)  // 10
#define G2_NT (V_DIM / G2_BN)     // 125
#define G2_NWG (G2_MT * G2_NT)    // 1250
#define G2_KT (D_DIM / G2_BK)     // 16

typedef __attribute__((ext_vector_type(8))) short bf16x8;
typedef __attribute__((ext_vector_type(4))) float f32x4;
typedef __attribute__((ext_vector_type(4))) uint16_t u16x4;

__device__ __forceinline__ uint16_t f2bf(float f) {
    union { float f; uint32_t u; } w; w.f = f;
    uint32_t r = (w.u + 0x7FFFu + ((w.u >> 16) & 1u)) >> 16;
    return (uint16_t)r;
}

__device__ __forceinline__ void async_copy16(const uint16_t* g, uint16_t* l) {
    __builtin_amdgcn_global_load_lds((const __attribute__((address_space(1))) void*)g,
                                     (__attribute__((address_space(3))) void*)l,
                                     16, 0, 0);
}

// ------- transpose+cast: in fp32 [R][C] -> out bf16 [C][R], 64x64 tiles ----
__global__ __launch_bounds__(256) void transpose_f32_bf16(const float* __restrict__ in,
                                                          uint16_t* __restrict__ out,
                                                          int R, int C) {
    __shared__ uint16_t tile[64][65];
    const int c0 = blockIdx.x * 64, r0 = blockIdx.y * 64;
    const int t  = threadIdx.x;
    const int lr = t >> 4;          // 0..15
    const int lc = (t & 15) * 4;    // 0..60
#pragma unroll
    for (int p = 0; p < 4; ++p) {
        const float* src = in + (size_t)(r0 + p * 16 + lr) * C + c0 + lc;
        f32x4 v = *(const f32x4*)src;
        tile[p * 16 + lr][lc + 0] = f2bf(v.x);
        tile[p * 16 + lr][lc + 1] = f2bf(v.y);
        tile[p * 16 + lr][lc + 2] = f2bf(v.z);
        tile[p * 16 + lr][lc + 3] = f2bf(v.w);
    }
    __syncthreads();
#pragma unroll
    for (int p = 0; p < 4; ++p) {
        const int oc = p * 16 + lr;  // col index within tile -> out row c0+oc
        u16x4 v;
        v.x = tile[lc + 0][oc];
        v.y = tile[lc + 1][oc];
        v.z = tile[lc + 2][oc];
        v.w = tile[lc + 3][oc];
        *(u16x4*)(out + (size_t)(c0 + oc) * R + r0 + lc) = v;
    }
}

// ------- gather+cast masked rows: Ag[r][:] = bf16(X[b, pos[r], :]) --------
__global__ __launch_bounds__(256) void gather_rows(const float* __restrict__ X,
                                                   const int* __restrict__ pos,
                                                   uint16_t* __restrict__ Ag) {
    const int r = blockIdx.x;
    const int t = threadIdx.x;
    size_t src = 0;
    if (r < ROWS) {
        const int b = r / M_TOK;
        const int p = pos[r];      // pos is [B][M] contiguous; flat idx == r
        src = ((size_t)b * S_DIM + p) * D_DIM;
    }
    f32x4 v = *(const f32x4*)(X + src + t * 4);
    u16x4 o;
    o.x = f2bf(v.x); o.y = f2bf(v.y); o.z = f2bf(v.z); o.w = f2bf(v.w);
    *(u16x4*)(Ag + (size_t)r * D_DIM + t * 4) = o;
}

// ------- m97-style GEMM (kept for the small GEMM1): C = A * B^T + bias ----
template <int EPI>
__global__ __launch_bounds__(256, 2) void gemm_bt(const uint16_t* __restrict__ A,
                                                  const uint16_t* __restrict__ B,
                                                  const float* __restrict__ bias,
                                                  float* __restrict__ C,
                                                  int K, int N, int MValid) {
    __shared__ uint16_t As[128 * 64];
    __shared__ uint16_t Bs[128 * 64];
    const int tid  = threadIdx.x;
    const int lane = tid & 63;
    const int wave = tid >> 6;
    const int wr   = (wave >> 1) * 64;
    const int wc   = (wave & 1) * 64;
    const int tM   = blockIdx.y * 128;
    const int tN   = blockIdx.x * 128;
    const int l15  = lane & 15;
    const int l4   = lane >> 4;

    const f32x4 zero = {0.f, 0.f, 0.f, 0.f};
    f32x4 acc[4][4];
#pragma unroll
    for (int i = 0; i < 4; ++i)
#pragma unroll
        for (int j = 0; j < 4; ++j) acc[i][j] = zero;

    const uint16_t* Agp = A + (size_t)(tM + (tid >> 3)) * K + (tid & 7) * 8;
    const uint16_t* Bgp = B + (size_t)(tN + (tid >> 3)) * K + (tid & 7) * 8;
    uint16_t* Asl = &As[tid * 8];
    uint16_t* Bsl = &Bs[tid * 8];
    const size_t rstep = (size_t)32 * K;

    for (int k0 = 0; k0 < K; k0 += 64) {
#pragma unroll
        for (int i = 0; i < 4; ++i)
            async_copy16(Agp + i * rstep + k0, Asl + i * 2048);
#pragma unroll
        for (int i = 0; i < 4; ++i)
            async_copy16(Bgp + i * rstep + k0, Bsl + i * 2048);
        __syncthreads();
#pragma unroll
        for (int kk = 0; kk < 2; ++kk) {
            bf16x8 af[4], bfr[4];
#pragma unroll
            for (int i = 0; i < 4; ++i)
                af[i] = *(const bf16x8*)&As[(wr + i * 16 + l15) * 64 + kk * 32 + l4 * 8];
#pragma unroll
            for (int j = 0; j < 4; ++j)
                bfr[j] = *(const bf16x8*)&Bs[(wc + j * 16 + l15) * 64 + kk * 32 + l4 * 8];
#pragma unroll
            for (int i = 0; i < 4; ++i)
#pragma unroll
                for (int j = 0; j < 4; ++j)
                    acc[i][j] = __builtin_amdgcn_mfma_f32_16x16x32_bf16(af[i], bfr[j],
                                                                        acc[i][j], 0, 0, 0);
        }
        __syncthreads();
    }

#pragma unroll
    for (int j = 0; j < 4; ++j) {
        const int col = tN + wc + j * 16 + l15;
        const float bv = bias[col];
#pragma unroll
        for (int i = 0; i < 4; ++i) {
            const int row0 = tM + wr + i * 16 + l4 * 4;
#pragma unroll
            for (int r = 0; r < 4; ++r) {
                const int row = row0 + r;
                float v = acc[i][j][r] + bv;
                if (EPI == 0) {
                    v = v > 0.f ? v : 0.f;
                    C[(size_t)row * N + col] = v;
                } else {
                    if (row < MValid)
                        C[(size_t)row * N + col] = v;
                }
            }
        }
    }
}

// ------- GEMM2: 256x256 tile, BK=64, 8 waves, 8-phase schedule, T2 swizzle -
// C[2560,32000] = A[2560,1024] * B^T[32000,1024] + bias, fp32 out, row mask.
// LDS 128 KiB: 2 x { A[256][64] | B[256][64] } bf16, XOR-swizzled columns.
__global__ __launch_bounds__(512, 2) void gemm2_256(const uint16_t* __restrict__ A,
                                                    const uint16_t* __restrict__ B,
                                                    const float* __restrict__ bias,
                                                    float* __restrict__ C,
                                                    int MValid) {
    __shared__ uint16_t lds[65536];   // 128 KiB
    const int tid  = threadIdx.x;
    const int lane = tid & 63;
    const int wave = tid >> 6;        // 0..7
    const int l15  = lane & 15;
    const int l4   = lane >> 4;       // 0..3
    const int R0   = (wave >> 2) * 128;  // wave row base (2 waves in M)
    const int C0   = (wave & 3) * 64;    // wave col base (4 waves in N)

    // T1: bijective XCD-chunked swizzle (m204); tm-fast => consecutive logical
    // blocks share the 512KB B-panel within one XCD's L2.
    const int bid = blockIdx.x;
    const int q = G2_NWG >> 3, r = G2_NWG & 7;
    const int xcd = bid & 7, lin = bid >> 3;
    const int wg = (xcd < r ? xcd * (q + 1) : r * (q + 1) + (xcd - r) * q) + lin;
    const int tM = (wg % G2_MT) * G2_BM;
    const int tN = (wg / G2_MT) * G2_BN;

    // Staging: linear LDS dest (global_load_lds requirement) + inverse-swizzled
    // GLOBAL source column. LDS element (row, ce) lives at row*64 + (ce ^ ((row&7)<<3)).
    const int srow = tid >> 3;                                        // 0..63
    const int scel = ((((tid & 7) << 4) ^ ((srow & 7) << 4)) >> 1);   // element col
    const uint16_t* Ags = A + (size_t)(tM + srow) * D_DIM + scel;
    const uint16_t* Bgs = B + (size_t)(tN + srow) * D_DIM + scel;
    uint16_t* AsD = &lds[tid * 8];
    uint16_t* BsD = &lds[16384 + tid * 8];

    const f32x4 zero = {0.f, 0.f, 0.f, 0.f};
    f32x4 acc[8][4];
#pragma unroll
    for (int i = 0; i < 8; ++i)
#pragma unroll
        for (int j = 0; j < 4; ++j) acc[i][j] = zero;

    // swizzled read column offsets (elements): kk=0 and kk=1
    const int colk0 = (l4 * 8) ^ ((l15 & 7) << 3);
    const int colk1 = colk0 ^ 32;

    // ---- prologue: stage K-tile 0 into buffer 0 ----
#pragma unroll
    for (int i = 0; i < 4; ++i)
        async_copy16(Ags + (size_t)(i * 64) * D_DIM, AsD + i * 4096);
#pragma unroll
    for (int i = 0; i < 4; ++i)
        async_copy16(Bgs + (size_t)(i * 64) * D_DIM, BsD + i * 4096);
    asm volatile("s_waitcnt vmcnt(0)" ::: "memory");
    __builtin_amdgcn_s_barrier();

#pragma unroll 2
    for (int t = 0; t < G2_KT; ++t) {
        const int bA = (t & 1) << 15;     // buffer base (u16 units)
        const int bB = bA + 16384;
        bf16x8 af[4], bf[4];

        // ---------- phase 0: kk=0, row-half 0; issue ALL next-tile stages ----------
#pragma unroll
        for (int i = 0; i < 4; ++i)
            af[i] = *(const bf16x8*)&lds[bA + (R0 + i * 16 + l15) * 64 + colk0];
#pragma unroll
        for (int j = 0; j < 4; ++j)
            bf[j] = *(const bf16x8*)&lds[bB + (C0 + j * 16 + l15) * 64 + colk0];
        if (t + 1 < G2_KT) {
            const int k0 = (t + 1) * G2_BK;
            const int sb = bA ^ 32768;
#pragma unroll
            for (int i = 0; i < 4; ++i)
                async_copy16(Ags + (size_t)(i * 64) * D_DIM + k0, AsD + sb + i * 4096);
#pragma unroll
            for (int i = 0; i < 4; ++i)
                async_copy16(Bgs + (size_t)(i * 64) * D_DIM + k0, BsD + sb + i * 4096);
        }
        __builtin_amdgcn_s_barrier();
        asm volatile("s_waitcnt lgkmcnt(0)" ::: "memory");
        __builtin_amdgcn_s_setprio(1);
#pragma unroll
        for (int i = 0; i < 4; ++i)
#pragma unroll
            for (int j = 0; j < 4; ++j)
                acc[i][j] = __builtin_amdgcn_mfma_f32_16x16x32_bf16(af[i], bf[j],
                                                                    acc[i][j], 0, 0, 0);
        __builtin_amdgcn_s_setprio(0);
        __builtin_amdgcn_s_barrier();

        // ---------- phase 1: kk=0, row-half 1 (reuse bf) ----------
#pragma unroll
        for (int i = 0; i < 4; ++i)
            af[i] = *(const bf16x8*)&lds[bA + (R0 + 64 + i * 16 + l15) * 64 + colk0];
        __builtin_amdgcn_s_barrier();
        asm volatile("s_waitcnt lgkmcnt(0)" ::: "memory");
        __builtin_amdgcn_s_setprio(1);
#pragma unroll
        for (int i = 0; i < 4; ++i)
#pragma unroll
            for (int j = 0; j < 4; ++j)
                acc[4 + i][j] = __builtin_amdgcn_mfma_f32_16x16x32_bf16(af[i], bf[j],
                                                                        acc[4 + i][j], 0, 0, 0);
        __builtin_amdgcn_s_setprio(0);
        __builtin_amdgcn_s_barrier();

        // ---------- phase 2: kk=1, row-half 0 ----------
#pragma unroll
        for (int i = 0; i < 4; ++i)
            af[i] = *(const bf16x8*)&lds[bA + (R0 + i * 16 + l15) * 64 + colk1];
#pragma unroll
        for (int j = 0; j < 4; ++j)
            bf[j] = *(const bf16x8*)&lds[bB + (C0 + j * 16 + l15) * 64 + colk1];
        __builtin_amdgcn_s_barrier();
        asm volatile("s_waitcnt lgkmcnt(0)" ::: "memory");
        __builtin_amdgcn_s_setprio(1);
#pragma unroll
        for (int i = 0; i < 4; ++i)
#pragma unroll
            for (int j = 0; j < 4; ++j)
                acc[i][j] = __builtin_amdgcn_mfma_f32_16x16x32_bf16(af[i], bf[j],
                                                                    acc[i][j], 0, 0, 0);
        __builtin_amdgcn_s_setprio(0);
        __builtin_amdgcn_s_barrier();

        // ---------- phase 3: kk=1, row-half 1; counted-drain at tile boundary ----------
#pragma unroll
        for (int i = 0; i < 4; ++i)
            af[i] = *(const bf16x8*)&lds[bA + (R0 + 64 + i * 16 + l15) * 64 + colk1];
        __builtin_amdgcn_s_barrier();
        asm volatile("s_waitcnt lgkmcnt(0)" ::: "memory");
        __builtin_amdgcn_s_setprio(1);
#pragma unroll
        for (int i = 0; i < 4; ++i)
#pragma unroll
            for (int j = 0; j < 4; ++j)
                acc[4 + i][j] = __builtin_amdgcn_mfma_f32_16x16x32_bf16(af[i], bf[j],
                                                                        acc[4 + i][j], 0, 0, 0);
        __builtin_amdgcn_s_setprio(0);
        // next-tile loads were issued ~3.5 phases ago -> this wait is near-free
        asm volatile("s_waitcnt vmcnt(0)" ::: "memory");
        __builtin_amdgcn_s_barrier();
    }

    // ---- epilogue: D mapping (16x16x32): row = l4*4 + rr, col = l15 ----
#pragma unroll
    for (int j = 0; j < 4; ++j) {
        const int col = tN + C0 + j * 16 + l15;
        const float bv = bias[col];
#pragma unroll
        for (int i = 0; i < 8; ++i) {
            const int row0 = tM + R0 + i * 16 + l4 * 4;
#pragma unroll
            for (int rr = 0; rr < 4; ++rr) {
                const int row = row0 + rr;
                if (row < MValid)
                    C[(size_t)row * V_DIM + col] = acc[i][j][rr] + bv;
            }
        }
    }
}

// ------- row LayerNorm: H fp32 [ROWS_PAD][1024] -> Hn bf16 ----------------
__global__ __launch_bounds__(256) void layernorm_rows(const float* __restrict__ H,
                                                      const float* __restrict__ gamma,
                                                      const float* __restrict__ beta,
                                                      uint16_t* __restrict__ Hn) {
    const int row = blockIdx.x;
    const int t   = threadIdx.x;
    const float* h = H + (size_t)row * D_DIM;
    f32x4 v = *(const f32x4*)(h + t * 4);
    float s  = v.x + v.y + v.z + v.w;
    float sq = v.x * v.x + v.y * v.y + v.z * v.z + v.w * v.w;
#pragma unroll
    for (int o = 32; o > 0; o >>= 1) {
        s  += __shfl_down(s, o, 64);
        sq += __shfl_down(sq, o, 64);
    }
    __shared__ float ss[4], sqs[4];
    if ((t & 63) == 0) { ss[t >> 6] = s; sqs[t >> 6] = sq; }
    __syncthreads();
    const float S    = ss[0] + ss[1] + ss[2] + ss[3];
    const float SQ   = sqs[0] + sqs[1] + sqs[2] + sqs[3];
    const float mean = S * (1.f / D_DIM);
    const float var  = SQ * (1.f / D_DIM) - mean * mean;
    const float rstd = rsqrtf(var + 1e-5f);
    const int c = t * 4;
    f32x4 g = *(const f32x4*)(gamma + c);
    f32x4 bt = *(const f32x4*)(beta + c);
    u16x4 o;
    o.x = f2bf((v.x - mean) * rstd * g.x + bt.x);
    o.y = f2bf((v.y - mean) * rstd * g.y + bt.y);
    o.z = f2bf((v.z - mean) * rstd * g.z + bt.z);
    o.w = f2bf((v.w - mean) * rstd * g.w + bt.w);
    *(u16x4*)(Hn + (size_t)row * D_DIM + c) = o;
}

extern "C" void kernel_launch(void* const* d_in, const int* in_sizes, int n_in,
                              void* d_out, int out_size, void* d_ws, size_t ws_size,
                              hipStream_t stream) {
    const float* X     = (const float*)d_in[0];
    const int*   mp    = (const int*)d_in[1];
    const float* W1    = (const float*)d_in[2];
    const float* b1    = (const float*)d_in[3];
    const float* gamma = (const float*)d_in[4];
    const float* beta  = (const float*)d_in[5];
    const float* W2    = (const float*)d_in[6];
    const float* b2    = (const float*)d_in[7];

    char* ws = (char*)d_ws;
    uint16_t* W2T = (uint16_t*)(ws);                                           // 65,536,000 B
    uint16_t* W1T = (uint16_t*)(ws + 65536000);                                //  2,097,152 B
    uint16_t* Ag  = (uint16_t*)(ws + 65536000 + 2097152);                      //  5,242,880 B
    uint16_t* Hn  = (uint16_t*)(ws + 65536000 + 2097152 + 5242880);            //  5,242,880 B
    float*    H   = (float*)   (ws + 65536000 + 2097152 + 5242880 + 5242880);  // 10,485,760 B

    // W2 fp32 [1024][32000] -> W2T bf16 [32000][1024]; W1 likewise
    transpose_f32_bf16<<<dim3(V_DIM / 64, D_DIM / 64), 256, 0, stream>>>(W2, W2T, D_DIM, V_DIM);
    transpose_f32_bf16<<<dim3(D_DIM / 64, D_DIM / 64), 256, 0, stream>>>(W1, W1T, D_DIM, D_DIM);
    // gather masked rows (padded to 2560 with row 0 data), cast to bf16
    gather_rows<<<ROWS_PAD, 256, 0, stream>>>(X, mp, Ag);
    // H = relu(Ag @ W1 + b1)   [2560][1024] fp32
    gemm_bt<0><<<dim3(D_DIM / 128, ROWS_PAD / 128), 256, 0, stream>>>(Ag, W1T, b1, H,
                                                                      D_DIM, D_DIM, ROWS_PAD);
    // Hn = LN(H) * gamma + beta  -> bf16
    layernorm_rows<<<ROWS_PAD, 256, 0, stream>>>(H, gamma, beta, Hn);
    // out = Hn @ W2 + b2  [2464][32000] fp32  (256^2 8-phase kernel)
    gemm2_256<<<dim3(G2_NWG), 512, 0, stream>>>(Hn, W2T, b2, (float*)d_out, ROWS);
}